// Round 3
// baseline (8651.471 us; speedup 1.0000x reference)
//
#include <hip/hip_runtime.h>
#include <stdint.h>
#include <stddef.h>

// ACT-LSTM, B=32 T=512 IN=50 H=512 OUT=66, MAX_PONDER=10, EPS=0.01, fp32.
// R14 = R13 resubmit (container infra failed twice; no kernel verdict).
// R13 = verified R11 protocol (LLC scope sc0 sc1 everywhere, gid=bid>>5)
//  + value-neutral wins only:
//   (1) block's 128 KB W_hh slice copied once into dynamic LDS -> GEMV reads
//       LDS (no per-phase 4 MB Wp stream through L2, no VMEM latency).
//   (2) flag poll issued by lanes 0..7 only (was 64) -> less LLC pressure.
//   (3) liveness budgets on all spins + cooperative-launch error fallback.
// R14 hardening: poll budget 50M -> 8M iters (~3 s worst-case degrade) and
// budget checked before sleeping, so any protocol stall exits promptly
// instead of risking a watchdog/container kill.

#define NBLK 256

// ---------------- ws layout (float offsets) ----------------
// wh   : [0, 8388608)            512*32*512  (32 MB)
// hbuf : [8388608, 8421376)      8 groups x 2 pp x 2048  ([k][4b] packing)
// bar  : [8421376, 8421888)      flags[256] (group G = [32G,32G+32)) + spare
// Wp   : [8421888, 9470464)      W_hh repacked [r][k4][c][kl]  (4 MB)
// W_iT : [9470464, 9574912)      51*2048     W_ih repacked [k][j*4+g]
// W_oT : [9574912, 9608704)      512*66      W_out transposed [k][o]
#define WS_NEED_BYTES 38434816ull

__device__ __forceinline__ float sigmf(float v) { return 1.0f / (1.0f + expf(-v)); }

// LLC-coherent (cross-XCD) stores: bypass L1+L2 (sc0 sc1).
__device__ __forceinline__ void store_llc(float* p, float v) {
  asm volatile("global_store_dword %0, %1, off sc0 sc1" :: "v"(p), "v"(v) : "memory");
}
__device__ __forceinline__ void store_llc_u(unsigned* p, unsigned v) {
  asm volatile("global_store_dword %0, %1, off sc0 sc1" :: "v"(p), "v"(v) : "memory");
}
// LLC-coherent load with the waitcnt fused INTO the asm (no reorder hazard).
__device__ __forceinline__ unsigned load_llc_u(const unsigned* p) {
  unsigned v;
  asm volatile("global_load_dword %0, %1, off sc0 sc1\ns_waitcnt vmcnt(0)"
               : "=&v"(v) : "v"(p) : "memory");
  return v;
}

#if defined(__has_builtin)
#if __has_builtin(__builtin_amdgcn_global_load_lds)
#define HAVE_GLLDS 1
#endif
#endif

// LLC-coherent global->LDS DMA, 16 B/lane. aux=0x11 = SC0|SC1.
__device__ __forceinline__ void stage_instr(const float* gp, float* lp) {
#ifdef HAVE_GLLDS
  __builtin_amdgcn_global_load_lds((const __attribute__((address_space(1))) unsigned int*)gp,
                                   (__attribute__((address_space(3))) unsigned int*)lp,
                                   16, 0, 0x11);
#else
  float4 tmp;
  asm volatile("global_load_dwordx4 %0, %1, off sc0 sc1" : "=v"(tmp) : "v"(gp) : "memory");
  asm volatile("s_waitcnt vmcnt(0)" ::: "memory");
  *(float4*)(lp + (threadIdx.x & 63) * 4) = tmp;
#endif
}

// ------------------------------------------------------------------
// prep: repack weights + zero flags.
// Wp[((r*128+k4)*64+c)*4+kl] = W_hh[((c&3)*512 + 16r + (c>>2))*512 + 4k4+kl]
__global__ void prep_k(const float* __restrict__ W_ih, const float* __restrict__ W_hh,
                       const float* __restrict__ W_out,
                       float* __restrict__ Wp, float* __restrict__ W_iT,
                       float* __restrict__ W_oT, unsigned* __restrict__ bar) {
  int idx = blockIdx.x * 256 + threadIdx.x;
  if (idx < 1048576) {
    int kl = idx & 3, c = (idx >> 2) & 63, k4 = (idx >> 8) & 127, r = idx >> 15;
    int row = (c & 3) * 512 + 16 * r + (c >> 2);
    Wp[idx] = W_hh[(size_t)row * 512 + 4 * k4 + kl];
  }
  int i2 = idx - 1048576;
  if (i2 >= 0 && i2 < 104448) {
    int col = i2 & 2047, k = i2 >> 11;
    int g = col & 3, j = col >> 2;
    W_iT[i2] = W_ih[(size_t)((g << 9) + j) * 51 + k];
  }
  int i3 = idx - 1153024;
  if (i3 >= 0 && i3 < 33792) {
    int k = i3 / 66, o = i3 - k * 66;
    W_oT[i3] = W_out[(size_t)o * 512 + k];
  }
  int i4 = idx - 1186816;
  if (i4 >= 0 && i4 < 512) bar[i4] = 0u;
}

// ------------------------------------------------------------------
// persistent ACT-LSTM: 256 blocks x 256 threads; group gid=bid>>5 (batches
// 4gid..4gid+3), rank r=bid&31 owns j in [16r,16r+16).
// (c,b)-role: c=tid&63 (col: g=c&3, jj=c>>2), batch=w=tid>>6. GEMV: thread
// computes col c x 4 batches over k-slice [128w,128w+128), weights from LDS.
// Owner lane (tid<64): jj=tid>>2, bo=tid&3 owns (batch 4gid+bo, j=16r+jj);
// its h2 slot is hbG + pp*2048 + 64r + tid (contiguous across lanes).
// Decision lanes tid<4 (batch=tid).
__global__ void __launch_bounds__(256)
act_main(const float* __restrict__ x, const float* __restrict__ bvec,
         const float* __restrict__ W_halt, const float* __restrict__ b_halt,
         const float* __restrict__ Wp, const float* __restrict__ W_iT,
         float* __restrict__ hbuf, unsigned* __restrict__ bar,
         float* __restrict__ wh, float* __restrict__ p_out) {
  extern __shared__ __align__(16) float wl[];  // 32768 f = 128 KB: Wp slice r
  __shared__ float hst[2048];        // staged h [k][4b], wave-private 2KB regions
  __shared__ float pacc[1024];       // GEMV partials [s][c][4b]
  __shared__ float xg2[256];         // final gate pre-acts [c][4b]
  __shared__ float hps[256];         // halt partials
  __shared__ float S_p[4];
  __shared__ int S_flag[1];

  const int tid = threadIdx.x, bid = blockIdx.x;
  const int gid = bid >> 5, r = bid & 31;
  const int c = tid & 63, w = tid >> 6, lane = tid & 63;
  const int jj = tid >> 2, bo = tid & 3;          // owner mapping (tid<64)
  const int ch = lane >> 2, b2 = lane & 3;        // halt-partial mapping
  unsigned* flags = bar + gid * 32;
  float* hbG = hbuf + gid * 4096;

  // ---- startup: copy this rank's Wp slice into LDS (32768 floats) ----
  {
    const float* wsrc = Wp + (size_t)r * 32768;
    for (int i = tid; i < 8192; i += 256)
      *(float4*)(wl + i * 4) = *(const float4*)(wsrc + i * 4);
  }

  const float bh = b_halt[0];
  const int cg = 64 * r + c;                       // W_iT column for (r,c)
  const float bs = bvec[(c & 3) * 512 + 16 * r + (c >> 2)];
  const float wfc = W_iT[50 * 2048 + cg];

  // (c,batch=w) state
  float gAcc = 0.f, gxc, gxn = 0.f;
  {  // x-projection for t=0, batch 4gid+w
    gxc = bs;
    const float* xr = x + (size_t)(gid * 4 + w) * 512 * 50;
    for (int k = 0; k < 50; ++k) gxc = fmaf(xr[k], W_iT[k * 2048 + cg], gxc);
  }
  // owner state (tid<64)
  float cS = 0.f, hprev = 0.f, acc_h = 0.f, acc_c = 0.f;
  // decision state (tid<4)
  float cum = 0.f, nupd = 0.f, rem = 0.f;
  int mydone = 0;

  int t = 0, n = 0, first = 1;
  unsigned ph = 0;
  long pollbud = 8000000L;             // liveness only; ~3 s worst case
  __syncthreads();

  while (true) {
    float val, cin = 0.f;
    if (first) {
      // phase 0: fresh step (t=0,n=0), h=0 -> gemm=0, gAcc=0
      val = gxc + wfc;
      first = 0;
    } else {
      // ---- per-wave poll: lanes 0..7 watch this wave's 8 producers ----
      {
        const unsigned* fp = flags + w * 8 + (lane & 7);
        while (true) {
          unsigned fv = 0u;
          if (lane < 8) fv = load_llc_u(fp);
          if (__ballot((lane < 8) ? (fv >= ph) : 1) == ~0ull) break;
          if (--pollbud < 0) break;    // liveness: degrade, never hang
          __builtin_amdgcn_s_sleep(1);
        }
      }
      // ---- stage own 2 KB (k in [128w,+128), [k][4b]) ----
      {
        const float* gp = hbG + ((ph & 1u) ^ 1u) * 2048 + w * 512 + lane * 4;
        float* lp = hst + w * 512;
        stage_instr(gp, lp); stage_instr(gp + 256, lp + 256);
      }
      // under the DMA: x-projection for t+1 (once per timestep)
      if (n == 0) {
        const int tn = (t + 1 > 511) ? 511 : t + 1;
        gxn = bs;
        const float* xr = x + ((size_t)(gid * 4 + w) * 512 + tn) * 50;
        for (int k = 0; k < 50; ++k) gxn = fmaf(xr[k], W_iT[k * 2048 + cg], gxn);
      }
      asm volatile("s_waitcnt vmcnt(0)" ::: "memory");

      // ---- GEMV slice: col c, 4 batches, k in [128w,+128), W from LDS ----
      {
        const float* wb = wl + w * 8192 + c * 4;
        const float* hb = hst + w * 512;
        float a0 = 0.f, a1 = 0.f, a2 = 0.f, a3 = 0.f;
        #pragma unroll 8
        for (int i = 0; i < 32; ++i) {
          const float4 wv = *(const float4*)(wb + i * 256);   // ds_read_b128
          const float4 h0 = *(const float4*)(hb + i * 16);    // wave-uniform
          const float4 h1 = *(const float4*)(hb + i * 16 + 4);
          const float4 h2v = *(const float4*)(hb + i * 16 + 8);
          const float4 h3 = *(const float4*)(hb + i * 16 + 12);
          a0 = fmaf(wv.x, h0.x, a0); a1 = fmaf(wv.x, h0.y, a1);
          a2 = fmaf(wv.x, h0.z, a2); a3 = fmaf(wv.x, h0.w, a3);
          a0 = fmaf(wv.y, h1.x, a0); a1 = fmaf(wv.y, h1.y, a1);
          a2 = fmaf(wv.y, h1.z, a2); a3 = fmaf(wv.y, h1.w, a3);
          a0 = fmaf(wv.z, h2v.x, a0); a1 = fmaf(wv.z, h2v.y, a1);
          a2 = fmaf(wv.z, h2v.z, a2); a3 = fmaf(wv.z, h2v.w, a3);
          a0 = fmaf(wv.w, h3.x, a0); a1 = fmaf(wv.w, h3.y, a1);
          a2 = fmaf(wv.w, h3.z, a2); a3 = fmaf(wv.w, h3.w, a3);
        }
        float4 pv; pv.x = a0; pv.y = a1; pv.z = a2; pv.w = a3;
        *(float4*)(pacc + w * 256 + c * 4) = pv;   // lanes contiguous
      }
      // ---- halt partial on own slice: k = 128w + ch + 16i ----
      {
        float hp = 0.f;
        #pragma unroll
        for (int i = 0; i < 8; ++i) {
          const int k = 128 * w + ch + 16 * i;
          hp = fmaf(hst[k * 4 + b2], W_halt[k], hp);
        }
        hps[tid] = hp;     // partial for batch lane&3
      }
      __syncthreads();   // sync_c

      // (c,w): reduce own gate over the 4 k-slices
      const float g = pacc[c * 4 + w] + pacc[256 + c * 4 + w] +
                      pacc[512 + c * 4 + w] + pacc[768 + c * 4 + w];
      // wave 0: ACT decision for the 4 batches
      if (tid < 64) {
        int vote = 1;
        if (tid < 4) {
          float d = 0.f;
          for (int m = 0; m < 64; ++m) d += hps[m * 4 + tid];
          const float halt = sigmf(d + bh);
          const int done = mydone;
          const int halted = ((cum + halt) > 0.99f) || (n == 9);
          S_p[tid] = done ? 0.f : (halted ? (1.f - cum) : halt);
          nupd += done ? 0.f : 1.f;
          rem += (done || !halted) ? 0.f : (1.f - cum);
          cum += done ? 0.f : halt;
          mydone = done | halted;
          vote = mydone;
        }
        const unsigned long long bal = __ballot(vote);
        if (tid == 0) S_flag[0] = (bal == ~0ull) ? 1 : 0;
      }
      __syncthreads();   // sync_d

      const int alldone = S_flag[0];
      const float p = S_p[w];
      gAcc = fmaf(p, g, gAcc);
      if (tid < 64) {    // owner accumulate (weighted h,c of staged step)
        const float po = S_p[bo];
        acc_h = fmaf(po, hprev, acc_h);
        acc_c = fmaf(po, cS, acc_c);
      }
      if (alldone) {     // timestep t ends; fresh step of t+1 this phase
        if (tid < 64) {
          wh[(size_t)t * 16384 + (size_t)(gid * 4 + bo) * 512 + 16 * r + jj] = acc_h;
          cin = acc_c;
          acc_h = 0.f; acc_c = 0.f;
        }
        if (r == 0 && tid < 4)
          p_out[(size_t)(gid * 4 + tid) * 512 + t] = nupd + rem;
        if (tid < 4) { cum = 0.f; nupd = 0.f; rem = 0.f; mydone = 0; }
        val = gxn + wfc + gAcc;      // fresh gates: no GEMM (linearity)
        gAcc = 0.f; gxc = gxn;
        t += 1; n = 0;
        if (t == 512) break;         // uniform within block & group
      } else {
        if (tid < 64) cin = cS;
        val = gxc + g;
        n += 1;
      }
    }

    xg2[c * 4 + w] = val;
    __syncthreads();   // sync_e
    if (tid < 64) {    // owner (jj,bo): cell step; publish h2 (coalesced); flag
      const float gi = xg2[16 * jj + 0 + bo];
      const float gf = xg2[16 * jj + 4 + bo];
      const float gg = xg2[16 * jj + 8 + bo];
      const float go = xg2[16 * jj + 12 + bo];
      const float c_new = sigmf(gf) * cin + sigmf(gi) * tanhf(gg);
      const float h_new = sigmf(go) * tanhf(c_new);
      cS = c_new; hprev = h_new;
      store_llc(hbG + (ph & 1u) * 2048 + 64 * r + tid, h_new);
      asm volatile("s_waitcnt vmcnt(0)" ::: "memory");
      if (tid == 0) store_llc_u(&flags[r], ph + 1u);
    }
    ph += 1;
  }
}

// ------------------------------------------------------------------
// epilogue: out[b,t,:] = seg-softmax(wh[t,b,:] @ W_out^T + b_out)
__global__ void __launch_bounds__(256)
epi_k(const float* __restrict__ wh, const float* __restrict__ W_oT,
      const float* __restrict__ b_out, float* __restrict__ out) {
  __shared__ float hl[4][512];
  __shared__ float yl[4][66];
  const int tid = threadIdx.x, pair = tid >> 6, lane = tid & 63;
  const int bt = blockIdx.x * 4 + pair;
  const int b = bt >> 9, t = bt & 511;
  const float* hsrc = wh + (size_t)t * 16384 + (size_t)b * 512;
  *(float4*)&hl[pair][lane * 8] = *(const float4*)(hsrc + lane * 8);
  *(float4*)&hl[pair][lane * 8 + 4] = *(const float4*)(hsrc + lane * 8 + 4);
  __syncthreads();
  if (lane < 33) {
    const int o = lane * 2;
    float y0 = b_out[o], y1 = b_out[o + 1];
    const float* hp_ = hl[pair];
    #pragma unroll 8
    for (int k = 0; k < 512; ++k) {
      const float h = hp_[k];
      const float2 wv = *(const float2*)(W_oT + k * 66 + o);
      y0 = fmaf(h, wv.x, y0);
      y1 = fmaf(h, wv.y, y1);
    }
    yl[pair][o] = y0; yl[pair][o + 1] = y1;
  }
  __syncthreads();
  if (tid < 24) {
    const int pr = tid / 6, g = tid - pr * 6;
    const int bt2 = blockIdx.x * 4 + pr;
    const float* yp = &yl[pr][g * 11];
    float m = yp[0];
    for (int u = 1; u < 11; ++u) m = fmaxf(m, yp[u]);
    float e[11], ssum = 0.f;
    for (int u = 0; u < 11; ++u) { e[u] = expf(yp[u] - m); ssum += e[u]; }
    const float inv = 1.0f / ssum;
    float* op = out + (size_t)bt2 * 66 + g * 11;
    for (int u = 0; u < 11; ++u) op[u] = e[u] * inv;
  }
}

// ------------------------------------------------------------------
extern "C" void kernel_launch(void* const* d_in, const int* in_sizes, int n_in,
                              void* d_out, int out_size, void* d_ws, size_t ws_size,
                              hipStream_t stream) {
  (void)in_sizes; (void)n_in; (void)out_size;
  const float* x      = (const float*)d_in[0];
  const float* W_ih   = (const float*)d_in[1];
  const float* W_hh   = (const float*)d_in[2];
  const float* bvec   = (const float*)d_in[3];
  const float* W_out  = (const float*)d_in[4];
  const float* b_out  = (const float*)d_in[5];
  const float* W_halt = (const float*)d_in[6];
  const float* b_halt = (const float*)d_in[7];
  float* out = (float*)d_out;
  float* ws  = (float*)d_ws;

  if (ws_size < (size_t)WS_NEED_BYTES) return;  // visible failure if ws too small

  float* wh     = ws;
  float* hbuf   = ws + 8388608;
  unsigned* bar = (unsigned*)(ws + 8421376);
  float* Wp     = ws + 8421888;
  float* W_iT   = ws + 9470464;
  float* W_oT   = ws + 9574912;
  float* p_out  = out + 1081344;  // B*T*OUT

  static int s_attr = 0;
  if (!s_attr) {
    (void)hipFuncSetAttribute((const void*)act_main,
                              hipFuncAttributeMaxDynamicSharedMemorySize, 131072);
    s_attr = 1;
  }

  hipLaunchKernelGGL(prep_k, dim3(4638), dim3(256), 0, stream,
                     W_ih, W_hh, W_out, Wp, W_iT, W_oT, bar);

  void* args[10];
  args[0] = (void*)&x;      args[1] = (void*)&bvec;  args[2] = (void*)&W_halt;
  args[3] = (void*)&b_halt; args[4] = (void*)&Wp;    args[5] = (void*)&W_iT;
  args[6] = (void*)&hbuf;   args[7] = (void*)&bar;   args[8] = (void*)&wh;
  args[9] = (void*)&p_out;
  hipError_t ce = hipLaunchCooperativeKernel((void*)act_main, dim3(NBLK), dim3(256),
                                             args, 131072, stream);
  if (ce != hipSuccess) {
    // fallback: plain launch (256 blocks, 1/CU -- co-resident in practice)
    hipLaunchKernelGGL(act_main, dim3(NBLK), dim3(256), 131072, stream,
                       x, bvec, W_halt, b_halt, Wp, W_iT, hbuf, bar, wh, p_out);
  }

  hipLaunchKernelGGL(epi_k, dim3(4096), dim3(256), 0, stream, wh, W_oT, b_out, out);
}

// Round 4
// 7030.392 us; speedup vs baseline: 1.2306x; 1.2306x over previous
//
#include <hip/hip_runtime.h>
#include <stdint.h>
#include <stddef.h>

// ACT-LSTM, B=32 T=512 IN=50 H=512 OUT=66, MAX_PONDER=10, EPS=0.01, fp32.
// R15: transport redesign. R13/14 profile: VALUBusy 9.4%, phase = 19.5k cy vs
// ~3.5k compute -> LLC sync chain + hot flag line dominates. Changes:
//  (1) stamped-line publish: producer h (64 floats) -> 5 x 64B lines, each
//      [15 payload | stamp]; ONE wave store (per-line 64B transactions are
//      atomic at the MALL) -> no vmcnt ack, no flag store, no flag line.
//  (2) consumers poll 40 per-producer stamp words (scattered, uncontended),
//      then bulk-read 2.5 KB once into regs and scatter to LDS.
//      Same pingpong parity + interlock (producer <=1 phase ahead) as the
//      verified flag protocol -> stamp>=ph validation equally safe.
//  (3) wave-parallel halt reduce (shfl_xor tree) replaces 64-iter serial.
//  (4) W_oT recomputed into dead Wp region AFTER act_main (prep2_k) to make
//      room for the stamped comm buffers; WS_NEED unchanged.
// Kept: W_hh slice in 128 KB LDS; liveness budgets; coop-launch fallback.

#define NBLK 256

// ---------------- ws layout (float offsets) ----------------
// wh   : [0, 8388608)            512*32*512  (32 MB)
// comm : [8388608, 8429568)      2 par x 256 producers x 80 words (stamped h)
// Wp   : [8429568, 9478144)      W_hh repacked [r][k4][c][kl]  (4 MB)
// W_iT : [9478144, 9582592)      51*2048
// W_oT : [8429568, 8463360)      written by prep2_k AFTER act_main (Wp dead)
#define WS_NEED_BYTES 38434816ull

__device__ __forceinline__ float sigmf(float v) { return 1.0f / (1.0f + expf(-v)); }

// LLC-coherent load with waitcnt fused into the asm (no reorder hazard).
__device__ __forceinline__ unsigned load_llc_u(const unsigned* p) {
  unsigned v;
  asm volatile("global_load_dword %0, %1, off sc0 sc1\ns_waitcnt vmcnt(0)"
               : "=&v"(v) : "v"(p) : "memory");
  return v;
}

// ------------------------------------------------------------------
// prep: repack weights + zero comm stamps.
__global__ void prep_k(const float* __restrict__ W_ih, const float* __restrict__ W_hh,
                       float* __restrict__ Wp, float* __restrict__ W_iT,
                       float* __restrict__ comm) {
  int idx = blockIdx.x * 256 + threadIdx.x;
  if (idx < 1048576) {
    int kl = idx & 3, c = (idx >> 2) & 63, k4 = (idx >> 8) & 127, r = idx >> 15;
    int row = (c & 3) * 512 + 16 * r + (c >> 2);
    Wp[idx] = W_hh[(size_t)row * 512 + 4 * k4 + kl];
  }
  int i2 = idx - 1048576;
  if (i2 >= 0 && i2 < 104448) {
    int col = i2 & 2047, k = i2 >> 11;
    int g = col & 3, j = col >> 2;
    W_iT[i2] = W_ih[(size_t)((g << 9) + j) * 51 + k];
  }
  int i3 = idx - 1153024;
  if (i3 >= 0 && i3 < 40960) comm[i3] = 0.0f;
}

// prep2: W_out^T into the dead Wp region (runs after act_main).
__global__ void prep2_k(const float* __restrict__ W_out, float* __restrict__ W_oT) {
  int i = blockIdx.x * 256 + threadIdx.x;
  if (i < 33792) {
    int k = i / 66, o = i - k * 66;
    W_oT[i] = W_out[(size_t)o * 512 + k];
  }
}

// ------------------------------------------------------------------
// persistent ACT-LSTM: 256 blocks x 256 threads; group gid=bid>>5 (batches
// 4gid..4gid+3), rank r=bid&31 owns j in [16r,16r+16).
// comm slot for (par, gid, r): 80 words = 5 lines of [15 payload | stamp].
// Payload order = owner v=tid<64 ((jj=v>>2, bo=v&3)): pos v -> line v/15,
// slot v%15. Consumer wave w handles producers q=8w..8w+7 (640 words).
__global__ void __launch_bounds__(256)
act_main(const float* __restrict__ x, const float* __restrict__ bvec,
         const float* __restrict__ W_halt, const float* __restrict__ b_halt,
         const float* __restrict__ Wp, const float* __restrict__ W_iT,
         float* __restrict__ comm, float* __restrict__ wh,
         float* __restrict__ p_out) {
  extern __shared__ __align__(16) float wl[];  // 32768 f = 128 KB: Wp slice r
  __shared__ float hst[2052];        // staged h [k][4b]; [2048] = dump slot
  __shared__ float pacc[1024];       // GEMV partials [s][c][4b]
  __shared__ float xg2[256];         // final gate pre-acts [c][4b]
  __shared__ float hps[256];         // halt partials
  __shared__ float pubf[80];         // publish staging (5 stamped lines)
  __shared__ float S_p[4];
  __shared__ int S_flag[1];

  const int tid = threadIdx.x, bid = blockIdx.x;
  const int gid = bid >> 5, r = bid & 31;
  const int c = tid & 63, w = tid >> 6, lane = tid & 63;
  const int jj = tid >> 2, bo = tid & 3;          // owner mapping (tid<64)
  const int ch = lane >> 2, b2 = lane & 3;        // halt-partial mapping

  // ---- startup: copy this rank's Wp slice into LDS (32768 floats) ----
  {
    const float* wsrc = Wp + (size_t)r * 32768;
    for (int i = tid; i < 8192; i += 256)
      *(float4*)(wl + i * 4) = *(const float4*)(wsrc + i * 4);
  }

  const float bh = b_halt[0];
  const int cg = 64 * r + c;
  const float bs = bvec[(c & 3) * 512 + 16 * r + (c >> 2)];
  const float wfc = W_iT[50 * 2048 + cg];

  // publish mapping (owner lane v=tid): line v/15, slot v%15
  const int pub_off = (tid / 15) * 16 + (tid % 15);
  // stamp-poll mapping (lane<40): producer q=lane/5, line j=lane%5
  const int sp_off = (lane / 5) * 80 + (lane % 5) * 16 + 15;

  // bulk word->hst mapping (per-thread constants; invalid -> dump 2048)
#define MKH(GW, DST) do { const int _q=(GW)/80, _o=(GW)%80, _li=_o>>4, _po=_o&15; \
    const int _pi = _li*15 + _po; \
    DST = ((_po < 15) && (_pi < 64)) ? (w*512 + _q*64 + _pi) : 2048; } while (0)
  int hA0,hA1,hA2,hA3,hB0,hB1,hB2,hB3;
  int hC0=2048,hC1=2048,hC2=2048,hC3=2048;
  MKH(4*lane+0,hA0); MKH(4*lane+1,hA1); MKH(4*lane+2,hA2); MKH(4*lane+3,hA3);
  MKH(256+4*lane+0,hB0); MKH(256+4*lane+1,hB1);
  MKH(256+4*lane+2,hB2); MKH(256+4*lane+3,hB3);
  if (lane < 32) {
    MKH(512+4*lane+0,hC0); MKH(512+4*lane+1,hC1);
    MKH(512+4*lane+2,hC2); MKH(512+4*lane+3,hC3);
  }
#undef MKH

  // (c,batch=w) state
  float gAcc = 0.f, gxc, gxn = 0.f;
  {  // x-projection for t=0, batch 4gid+w
    gxc = bs;
    const float* xr = x + (size_t)(gid * 4 + w) * 512 * 50;
    for (int k = 0; k < 50; ++k) gxc = fmaf(xr[k], W_iT[k * 2048 + cg], gxc);
  }
  // owner state (tid<64)
  float cS = 0.f, hprev = 0.f, acc_h = 0.f, acc_c = 0.f;
  // decision state (tid<4)
  float cum = 0.f, nupd = 0.f, rem = 0.f;
  int mydone = 0;

  int t = 0, n = 0, first = 1;
  unsigned ph = 0;
  long pollbud = 8000000L;             // liveness only; ~3 s worst case
  __syncthreads();

  while (true) {
    float val, cin = 0.f;
    if (first) {
      val = gxc + wfc;                 // phase 0: h=0 -> gemm=0
      first = 0;
    } else {
      const unsigned par_rd = (ph & 1u) ^ 1u;
      const float* cb = comm + (size_t)(par_rd * 256u + gid * 32 + 8 * w) * 80;
      // ---- stamp poll: lanes 0..39 watch 8 producers x 5 lines ----
      {
        const unsigned* stp = (const unsigned*)cb + sp_off;
        while (true) {
          unsigned sv = 0u;
          if (lane < 40) sv = load_llc_u(stp);
          if (__ballot((lane < 40) ? (sv >= ph) : 1) == ~0ull) break;
          if (--pollbud < 0) break;    // liveness: degrade, never hang
          __builtin_amdgcn_s_sleep(1);
        }
      }
      // ---- bulk read 640 words (payload+stamps) into regs ----
      float4 vA, vB, vC;
      asm volatile("global_load_dwordx4 %0, %1, off sc0 sc1"
                   : "=v"(vA) : "v"(cb + 4 * lane) : "memory");
      asm volatile("global_load_dwordx4 %0, %1, off sc0 sc1"
                   : "=v"(vB) : "v"(cb + 256 + 4 * lane) : "memory");
      if (lane < 32)
        asm volatile("global_load_dwordx4 %0, %1, off sc0 sc1"
                     : "=v"(vC) : "v"(cb + 512 + 4 * lane) : "memory");
      // under the loads: x-projection for t+1 (once per timestep)
      if (n == 0) {
        const int tn = (t + 1 > 511) ? 511 : t + 1;
        gxn = bs;
        const float* xr = x + ((size_t)(gid * 4 + w) * 512 + tn) * 50;
        for (int k = 0; k < 50; ++k) gxn = fmaf(xr[k], W_iT[k * 2048 + cg], gxn);
      }
      asm volatile("s_waitcnt vmcnt(0)" ::: "memory");
      // ---- scatter payload into hst [k][4b] (own wave region) ----
      hst[hA0] = vA.x; hst[hA1] = vA.y; hst[hA2] = vA.z; hst[hA3] = vA.w;
      hst[hB0] = vB.x; hst[hB1] = vB.y; hst[hB2] = vB.z; hst[hB3] = vB.w;
      if (lane < 32) {
        hst[hC0] = vC.x; hst[hC1] = vC.y; hst[hC2] = vC.z; hst[hC3] = vC.w;
      }

      // ---- GEMV slice: col c, 4 batches, k in [128w,+128), W from LDS ----
      {
        const float* wb = wl + w * 8192 + c * 4;
        const float* hb = hst + w * 512;
        float a0 = 0.f, a1 = 0.f, a2 = 0.f, a3 = 0.f;
        #pragma unroll 8
        for (int i = 0; i < 32; ++i) {
          const float4 wv = *(const float4*)(wb + i * 256);   // ds_read_b128
          const float4 h0 = *(const float4*)(hb + i * 16);    // wave-uniform
          const float4 h1 = *(const float4*)(hb + i * 16 + 4);
          const float4 h2v = *(const float4*)(hb + i * 16 + 8);
          const float4 h3 = *(const float4*)(hb + i * 16 + 12);
          a0 = fmaf(wv.x, h0.x, a0); a1 = fmaf(wv.x, h0.y, a1);
          a2 = fmaf(wv.x, h0.z, a2); a3 = fmaf(wv.x, h0.w, a3);
          a0 = fmaf(wv.y, h1.x, a0); a1 = fmaf(wv.y, h1.y, a1);
          a2 = fmaf(wv.y, h1.z, a2); a3 = fmaf(wv.y, h1.w, a3);
          a0 = fmaf(wv.z, h2v.x, a0); a1 = fmaf(wv.z, h2v.y, a1);
          a2 = fmaf(wv.z, h2v.z, a2); a3 = fmaf(wv.z, h2v.w, a3);
          a0 = fmaf(wv.w, h3.x, a0); a1 = fmaf(wv.w, h3.y, a1);
          a2 = fmaf(wv.w, h3.z, a2); a3 = fmaf(wv.w, h3.w, a3);
        }
        float4 pv; pv.x = a0; pv.y = a1; pv.z = a2; pv.w = a3;
        *(float4*)(pacc + w * 256 + c * 4) = pv;
      }
      // ---- halt partial on own slice: k = 128w + ch + 16i ----
      {
        float hp = 0.f;
        #pragma unroll
        for (int i = 0; i < 8; ++i) {
          const int k = 128 * w + ch + 16 * i;
          hp = fmaf(hst[k * 4 + b2], W_halt[k], hp);
        }
        hps[tid] = hp;
      }
      __syncthreads();   // sync_c

      const float g = pacc[c * 4 + w] + pacc[256 + c * 4 + w] +
                      pacc[512 + c * 4 + w] + pacc[768 + c * 4 + w];
      // wave 0: parallel halt reduce + ACT decision for the 4 batches
      if (tid < 64) {
        float s = hps[tid] + hps[tid + 64] + hps[tid + 128] + hps[tid + 192];
        s += __shfl_xor(s, 4);  s += __shfl_xor(s, 8);
        s += __shfl_xor(s, 16); s += __shfl_xor(s, 32);
        int vote = 1;
        if (tid < 4) {
          const float halt = sigmf(s + bh);
          const int done = mydone;
          const int halted = ((cum + halt) > 0.99f) || (n == 9);
          S_p[tid] = done ? 0.f : (halted ? (1.f - cum) : halt);
          nupd += done ? 0.f : 1.f;
          rem += (done || !halted) ? 0.f : (1.f - cum);
          cum += done ? 0.f : halt;
          mydone = done | halted;
          vote = mydone;
        }
        const unsigned long long bal = __ballot(vote);
        if (tid == 0) S_flag[0] = (bal == ~0ull) ? 1 : 0;
      }
      __syncthreads();   // sync_d

      const int alldone = S_flag[0];
      const float p = S_p[w];
      gAcc = fmaf(p, g, gAcc);
      if (tid < 64) {
        const float po = S_p[bo];
        acc_h = fmaf(po, hprev, acc_h);
        acc_c = fmaf(po, cS, acc_c);
      }
      if (alldone) {
        if (tid < 64) {
          wh[(size_t)t * 16384 + (size_t)(gid * 4 + bo) * 512 + 16 * r + jj] = acc_h;
          cin = acc_c;
          acc_h = 0.f; acc_c = 0.f;
        }
        if (r == 0 && tid < 4)
          p_out[(size_t)(gid * 4 + tid) * 512 + t] = nupd + rem;
        if (tid < 4) { cum = 0.f; nupd = 0.f; rem = 0.f; mydone = 0; }
        val = gxn + wfc + gAcc;      // fresh gates: no GEMM (linearity)
        gAcc = 0.f; gxc = gxn;
        t += 1; n = 0;
        if (t == 512) break;         // uniform within block & group
      } else {
        if (tid < 64) cin = cS;
        val = gxc + g;
        n += 1;
      }
    }

    xg2[c * 4 + w] = val;
    __syncthreads();   // sync_e
    if (tid < 64) {    // owner (jj,bo): cell step; stage stamped publish
      const float gi = xg2[16 * jj + 0 + bo];
      const float gf = xg2[16 * jj + 4 + bo];
      const float gg = xg2[16 * jj + 8 + bo];
      const float go = xg2[16 * jj + 12 + bo];
      const float c_new = sigmf(gf) * cin + sigmf(gi) * tanhf(gg);
      const float h_new = sigmf(go) * tanhf(c_new);
      cS = c_new; hprev = h_new;
      pubf[pub_off] = h_new;
      if (tid < 5) pubf[tid * 16 + 15] = __uint_as_float(ph + 1u);
    }
    // wave-0-internal LDS fence, then one-instruction 5-line publish
    asm volatile("s_waitcnt lgkmcnt(0)" ::: "memory");
    __builtin_amdgcn_sched_barrier(0);
    if (tid < 40) {
      const float2 pv = *(const float2*)&pubf[2 * tid];
      float* cp = comm + (size_t)((ph & 1u) * 256u + gid * 32 + r) * 80 + 2 * tid;
      asm volatile("global_store_dwordx2 %0, %1, off sc0 sc1"
                   :: "v"(cp), "v"(pv) : "memory");
    }
    ph += 1;
  }
}

// ------------------------------------------------------------------
// epilogue: out[b,t,:] = seg-softmax(wh[t,b,:] @ W_out^T + b_out)
__global__ void __launch_bounds__(256)
epi_k(const float* __restrict__ wh, const float* __restrict__ W_oT,
      const float* __restrict__ b_out, float* __restrict__ out) {
  __shared__ float hl[4][512];
  __shared__ float yl[4][66];
  const int tid = threadIdx.x, pair = tid >> 6, lane = tid & 63;
  const int bt = blockIdx.x * 4 + pair;
  const int b = bt >> 9, t = bt & 511;
  const float* hsrc = wh + (size_t)t * 16384 + (size_t)b * 512;
  *(float4*)&hl[pair][lane * 8] = *(const float4*)(hsrc + lane * 8);
  *(float4*)&hl[pair][lane * 8 + 4] = *(const float4*)(hsrc + lane * 8 + 4);
  __syncthreads();
  if (lane < 33) {
    const int o = lane * 2;
    float y0 = b_out[o], y1 = b_out[o + 1];
    const float* hp_ = hl[pair];
    #pragma unroll 8
    for (int k = 0; k < 512; ++k) {
      const float h = hp_[k];
      const float2 wv = *(const float2*)(W_oT + k * 66 + o);
      y0 = fmaf(h, wv.x, y0);
      y1 = fmaf(h, wv.y, y1);
    }
    yl[pair][o] = y0; yl[pair][o + 1] = y1;
  }
  __syncthreads();
  if (tid < 24) {
    const int pr = tid / 6, g = tid - pr * 6;
    const int bt2 = blockIdx.x * 4 + pr;
    const float* yp = &yl[pr][g * 11];
    float m = yp[0];
    for (int u = 1; u < 11; ++u) m = fmaxf(m, yp[u]);
    float e[11], ssum = 0.f;
    for (int u = 0; u < 11; ++u) { e[u] = expf(yp[u] - m); ssum += e[u]; }
    const float inv = 1.0f / ssum;
    float* op = out + (size_t)bt2 * 66 + g * 11;
    for (int u = 0; u < 11; ++u) op[u] = e[u] * inv;
  }
}

// ------------------------------------------------------------------
extern "C" void kernel_launch(void* const* d_in, const int* in_sizes, int n_in,
                              void* d_out, int out_size, void* d_ws, size_t ws_size,
                              hipStream_t stream) {
  (void)in_sizes; (void)n_in; (void)out_size;
  const float* x      = (const float*)d_in[0];
  const float* W_ih   = (const float*)d_in[1];
  const float* W_hh   = (const float*)d_in[2];
  const float* bvec   = (const float*)d_in[3];
  const float* W_out  = (const float*)d_in[4];
  const float* b_out  = (const float*)d_in[5];
  const float* W_halt = (const float*)d_in[6];
  const float* b_halt = (const float*)d_in[7];
  float* out = (float*)d_out;
  float* ws  = (float*)d_ws;

  if (ws_size < (size_t)WS_NEED_BYTES) return;  // visible failure if ws too small

  float* wh   = ws;
  float* comm = ws + 8388608;
  float* Wp   = ws + 8429568;
  float* W_iT = ws + 9478144;
  float* W_oT = ws + 8429568;     // epi-time alias of Wp (written by prep2_k)
  float* p_out = out + 1081344;   // B*T*OUT

  static int s_attr = 0;
  if (!s_attr) {
    (void)hipFuncSetAttribute((const void*)act_main,
                              hipFuncAttributeMaxDynamicSharedMemorySize, 131072);
    s_attr = 1;
  }

  hipLaunchKernelGGL(prep_k, dim3(4664), dim3(256), 0, stream,
                     W_ih, W_hh, Wp, W_iT, comm);

  void* args[9];
  args[0] = (void*)&x;      args[1] = (void*)&bvec;  args[2] = (void*)&W_halt;
  args[3] = (void*)&b_halt; args[4] = (void*)&Wp;    args[5] = (void*)&W_iT;
  args[6] = (void*)&comm;   args[7] = (void*)&wh;    args[8] = (void*)&p_out;
  hipError_t ce = hipLaunchCooperativeKernel((void*)act_main, dim3(NBLK), dim3(256),
                                             args, 131072, stream);
  if (ce != hipSuccess) {
    hipLaunchKernelGGL(act_main, dim3(NBLK), dim3(256), 131072, stream,
                       x, bvec, W_halt, b_halt, Wp, W_iT, comm, wh, p_out);
  }

  hipLaunchKernelGGL(prep2_k, dim3(132), dim3(256), 0, stream, W_out, W_oT);
  hipLaunchKernelGGL(epi_k, dim3(4096), dim3(256), 0, stream, wh, W_oT, b_out, out);
}